// Round 1
// baseline (711.574 us; speedup 1.0000x reference)
//
#include <hip/hip_runtime.h>
#include <hip/hip_bf16.h>

#define BDIM 8
#define NTOK 8192
#define CDIM 256
#define HEADS 4
#define DHEAD 64
#define MROWS (BDIM * NTOK)   // 65536

// ---------------------------------------------------------------------------
// zero a float buffer
__global__ __launch_bounds__(256) void zero_kernel(float* __restrict__ p, int n) {
    int i = blockIdx.x * 256 + threadIdx.x;
    if (i < n) p[i] = 0.0f;
}

// ---------------------------------------------------------------------------
// K1: projection GEMM. out[m][c] = sum_k A[m][k] * W[c][k]  (torch Linear: x @ W^T)
// M=65536, K=256, N=256. BM=BN=64, BK=16, 256 threads, 4x4 acc per thread.
// z=0: q=x1*Wq^T (+sumsq), z=1: k=x2*Wk^T (+sumsq), z=2: v=x2*Wv^T
__global__ __launch_bounds__(256) void proj_gemm(
    const float* __restrict__ x1, const float* __restrict__ x2,
    const float* __restrict__ Wq, const float* __restrict__ Wk,
    const float* __restrict__ Wv,
    __hip_bfloat16* __restrict__ qp, __hip_bfloat16* __restrict__ kp,
    __hip_bfloat16* __restrict__ vp,
    float* __restrict__ ssq, float* __restrict__ ssk)
{
    const float* A;
    const float* W;
    __hip_bfloat16* outp;
    float* ss;
    if (blockIdx.z == 0)      { A = x1; W = Wq; outp = qp; ss = ssq; }
    else if (blockIdx.z == 1) { A = x2; W = Wk; outp = kp; ss = ssk; }
    else                      { A = x2; W = Wv; outp = vp; ss = nullptr; }

    __shared__ float As[16][68];
    __shared__ float Bs[16][68];
    __shared__ float colss[64];

    const int t  = threadIdx.x;
    const int tx = t & 15, ty = t >> 4;
    const int m0 = blockIdx.x * 64;
    const int c0 = blockIdx.y * 64;

    float acc[4][4] = {};

    for (int k0 = 0; k0 < CDIM; k0 += 16) {
#pragma unroll
        for (int r = 0; r < 4; ++r) {
            int idx = t + r * 256;      // 0..1023
            int ml = idx >> 4;          // 0..63
            int kl = idx & 15;          // 0..15
            As[kl][ml] = A[(size_t)(m0 + ml) * CDIM + (k0 + kl)];
            Bs[kl][ml] = W[(size_t)(c0 + ml) * CDIM + (k0 + kl)];
        }
        __syncthreads();
#pragma unroll
        for (int kk = 0; kk < 16; ++kk) {
            float4 a = *(const float4*)&As[kk][ty * 4];
            float4 b = *(const float4*)&Bs[kk][tx * 4];
            float av[4] = {a.x, a.y, a.z, a.w};
            float bv[4] = {b.x, b.y, b.z, b.w};
#pragma unroll
            for (int i = 0; i < 4; ++i)
#pragma unroll
                for (int j = 0; j < 4; ++j)
                    acc[i][j] += av[i] * bv[j];
        }
        __syncthreads();
    }

    // write bf16 projection
#pragma unroll
    for (int i = 0; i < 4; ++i) {
        int m = m0 + ty * 4 + i;
#pragma unroll
        for (int j = 0; j < 4; ++j) {
            outp[(size_t)m * CDIM + c0 + tx * 4 + j] = __float2bfloat16(acc[i][j]);
        }
    }

    // fused per-column sum-of-squares (norm over token axis)
    if (ss) {
        if (t < 64) colss[t] = 0.0f;
        __syncthreads();
#pragma unroll
        for (int j = 0; j < 4; ++j) {
            float s = 0.0f;
#pragma unroll
            for (int i = 0; i < 4; ++i) s += acc[i][j] * acc[i][j];
            atomicAdd(&colss[tx * 4 + j], s);
        }
        __syncthreads();
        if (t < 64) {
            int b = m0 / NTOK;          // 64-row tile never crosses a batch
            atomicAdd(&ss[b * CDIM + c0 + t], colss[t]);
        }
    }
}

// ---------------------------------------------------------------------------
// K2: Gram matrix. G[b][h][d][e] += sum_{n in slab} qp[b][n][h*64+d] * kp[b][n][h*64+e]
// grid (16 slabs, H, B), 256 threads, 64x64 acc per block (4x4/thread), n-chunk 32.
__global__ __launch_bounds__(256) void gram_kernel(
    const __hip_bfloat16* __restrict__ qp, const __hip_bfloat16* __restrict__ kp,
    float* __restrict__ G)
{
    __shared__ float qs[32][68];
    __shared__ float ks[32][68];

    const int t  = threadIdx.x;
    const int tx = t & 15, ty = t >> 4;
    const int slab = blockIdx.x;
    const int h = blockIdx.y;
    const int b = blockIdx.z;
    const size_t base = (size_t)b * NTOK * CDIM + h * DHEAD;

    float acc[4][4] = {};

    for (int n0 = slab * 512; n0 < slab * 512 + 512; n0 += 32) {
#pragma unroll
        for (int r = 0; r < 8; ++r) {
            int idx = t + r * 256;      // 0..2047
            int nn = idx >> 6;          // 0..31
            int cc = idx & 63;          // 0..63
            size_t g = base + (size_t)(n0 + nn) * CDIM + cc;
            qs[nn][cc] = __bfloat162float(qp[g]);
            ks[nn][cc] = __bfloat162float(kp[g]);
        }
        __syncthreads();
#pragma unroll
        for (int nn = 0; nn < 32; ++nn) {
            float4 a  = *(const float4*)&qs[nn][ty * 4];
            float4 bb = *(const float4*)&ks[nn][tx * 4];
            float av[4] = {a.x, a.y, a.z, a.w};
            float bv[4] = {bb.x, bb.y, bb.z, bb.w};
#pragma unroll
            for (int i = 0; i < 4; ++i)
#pragma unroll
                for (int j = 0; j < 4; ++j)
                    acc[i][j] += av[i] * bv[j];
        }
        __syncthreads();
    }

    float* Gp = G + (size_t)(b * HEADS + h) * DHEAD * DHEAD;
#pragma unroll
    for (int i = 0; i < 4; ++i)
#pragma unroll
        for (int j = 0; j < 4; ++j)
            atomicAdd(&Gp[(ty * 4 + i) * DHEAD + tx * 4 + j], acc[i][j]);
}

// ---------------------------------------------------------------------------
// K3: normalize by L2 norms (clamped at 1e-12), scale by temperature, row softmax.
// grid (H, B), 64 threads = one row d per thread.
__global__ __launch_bounds__(64) void attn_softmax(
    float* __restrict__ G, const float* __restrict__ ssq,
    const float* __restrict__ ssk, const float* __restrict__ temp)
{
    const int h = blockIdx.x, b = blockIdx.y;
    const int d = threadIdx.x;
    __shared__ float nk[64];

    float nq = fmaxf(sqrtf(ssq[b * CDIM + h * DHEAD + d]), 1e-12f);
    nk[d]    = fmaxf(sqrtf(ssk[b * CDIM + h * DHEAD + d]), 1e-12f);
    __syncthreads();

    float* row = G + (size_t)(b * HEADS + h) * DHEAD * DHEAD + d * DHEAD;
    const float tmp = temp[h];

    float vals[64];
    float mx = -1e30f;
#pragma unroll
    for (int e = 0; e < 64; ++e) {
        float v = row[e] / (nq * nk[e]) * tmp;
        vals[e] = v;
        mx = fmaxf(mx, v);
    }
    float s = 0.0f;
#pragma unroll
    for (int e = 0; e < 64; ++e) {
        float ev = __expf(vals[e] - mx);
        vals[e] = ev;
        s += ev;
    }
    float inv = 1.0f / s;
#pragma unroll
    for (int e = 0; e < 64; ++e) row[e] = vals[e] * inv;
}

// ---------------------------------------------------------------------------
// K4: W_eff[b][c][h*64+e] = sum_d Wo[c][h*64+d] * attn[b][h][d][e]
// grid (H, B), 256 threads (one c per thread).
__global__ __launch_bounds__(256) void weff_kernel(
    const float* __restrict__ Wo, const float* __restrict__ attn,
    float* __restrict__ Weff)
{
    const int h = blockIdx.x, b = blockIdx.y;
    const int c = threadIdx.x;
    __shared__ float at[64][65];

    const float* Ab = attn + (size_t)(b * HEADS + h) * DHEAD * DHEAD;
    for (int idx = c; idx < DHEAD * DHEAD; idx += 256)
        at[idx >> 6][idx & 63] = Ab[idx];
    __syncthreads();

    float wo[64];
#pragma unroll
    for (int d2 = 0; d2 < 64; ++d2) wo[d2] = Wo[(size_t)c * CDIM + h * DHEAD + d2];

    float* Wb = Weff + (size_t)b * CDIM * CDIM + (size_t)c * CDIM + h * DHEAD;
#pragma unroll 4
    for (int e = 0; e < 64; ++e) {
        float s = 0.0f;
#pragma unroll
        for (int d2 = 0; d2 < 64; ++d2) s += wo[d2] * at[d2][e];
        Wb[e] = s;
    }
}

// ---------------------------------------------------------------------------
// K5: out[m][c] = bo[c] + sum_{c'} vp[m][c'] * Weff[b][c][c'],  b = m / NTOK
__global__ __launch_bounds__(256) void out_gemm(
    const __hip_bfloat16* __restrict__ vp, const float* __restrict__ Weff,
    const float* __restrict__ bo, float* __restrict__ out)
{
    __shared__ float As[16][68];
    __shared__ float Bs[16][68];

    const int t  = threadIdx.x;
    const int tx = t & 15, ty = t >> 4;
    const int m0 = blockIdx.x * 64;
    const int c0 = blockIdx.y * 64;
    const int b  = m0 / NTOK;
    const float* Wb = Weff + (size_t)b * CDIM * CDIM;

    float acc[4][4] = {};

    for (int k0 = 0; k0 < CDIM; k0 += 16) {
#pragma unroll
        for (int r = 0; r < 4; ++r) {
            int idx = t + r * 256;
            int ml = idx >> 4;
            int kl = idx & 15;
            As[kl][ml] = __bfloat162float(vp[(size_t)(m0 + ml) * CDIM + (k0 + kl)]);
            Bs[kl][ml] = Wb[(size_t)(c0 + ml) * CDIM + (k0 + kl)];
        }
        __syncthreads();
#pragma unroll
        for (int kk = 0; kk < 16; ++kk) {
            float4 a = *(const float4*)&As[kk][ty * 4];
            float4 b4 = *(const float4*)&Bs[kk][tx * 4];
            float av[4] = {a.x, a.y, a.z, a.w};
            float bv[4] = {b4.x, b4.y, b4.z, b4.w};
#pragma unroll
            for (int i = 0; i < 4; ++i)
#pragma unroll
                for (int j = 0; j < 4; ++j)
                    acc[i][j] += av[i] * bv[j];
        }
        __syncthreads();
    }

#pragma unroll
    for (int i = 0; i < 4; ++i) {
        int m = m0 + ty * 4 + i;
#pragma unroll
        for (int j = 0; j < 4; ++j) {
            int c = c0 + tx * 4 + j;
            out[(size_t)m * CDIM + c] = acc[i][j] + bo[c];
        }
    }
}

// ---------------------------------------------------------------------------
extern "C" void kernel_launch(void* const* d_in, const int* in_sizes, int n_in,
                              void* d_out, int out_size, void* d_ws, size_t ws_size,
                              hipStream_t stream) {
    const float* x1   = (const float*)d_in[0];
    const float* x2   = (const float*)d_in[1];
    const float* Wq   = (const float*)d_in[2];
    const float* Wk   = (const float*)d_in[3];
    const float* Wv   = (const float*)d_in[4];
    const float* Wo   = (const float*)d_in[5];
    const float* bo   = (const float*)d_in[6];
    const float* temp = (const float*)d_in[7];
    float* out = (float*)d_out;

    // workspace layout (bytes)
    char* ws = (char*)d_ws;
    const size_t SZ_PROJ = (size_t)MROWS * CDIM * sizeof(__hip_bfloat16);  // 33554432
    __hip_bfloat16* qp = (__hip_bfloat16*)(ws);
    __hip_bfloat16* kp = (__hip_bfloat16*)(ws + SZ_PROJ);
    __hip_bfloat16* vp = (__hip_bfloat16*)(ws + 2 * SZ_PROJ);
    float* ssq  = (float*)(ws + 3 * SZ_PROJ);                       // B*C floats
    float* ssk  = (float*)(ws + 3 * SZ_PROJ + 8192);
    float* G    = (float*)(ws + 3 * SZ_PROJ + 16384);               // B*H*64*64 floats
    float* Weff = (float*)(ws + 3 * SZ_PROJ + 16384 + 524288);      // B*C*C floats

    // zero ssq, ssk, G (contiguous region of (8192+8192+524288)/4 = 135168 floats)
    {
        int nz = 135168;
        zero_kernel<<<dim3((nz + 255) / 256), dim3(256), 0, stream>>>(ssq, nz);
    }

    proj_gemm<<<dim3(MROWS / 64, CDIM / 64, 3), dim3(256), 0, stream>>>(
        x1, x2, Wq, Wk, Wv, qp, kp, vp, ssq, ssk);

    gram_kernel<<<dim3(16, HEADS, BDIM), dim3(256), 0, stream>>>(qp, kp, G);

    attn_softmax<<<dim3(HEADS, BDIM), dim3(64), 0, stream>>>(G, ssq, ssk, temp);

    weff_kernel<<<dim3(HEADS, BDIM), dim3(256), 0, stream>>>(Wo, G, Weff);

    out_gemm<<<dim3(MROWS / 64, CDIM / 64), dim3(256), 0, stream>>>(vp, Weff, bo, out);
}

// Round 2
// 367.798 us; speedup vs baseline: 1.9347x; 1.9347x over previous
//
#include <hip/hip_runtime.h>
#include <hip/hip_bf16.h>

#define BDIM 8
#define NTOK 8192
#define CDIM 256
#define HEADS 4
#define DHEAD 64
#define MROWS (BDIM * NTOK)   // 65536

typedef unsigned short ushort_t;
typedef short bf16x8 __attribute__((ext_vector_type(8)));
typedef float f32x4 __attribute__((ext_vector_type(4)));
typedef unsigned short u16x8 __attribute__((ext_vector_type(8)));

// async global->LDS, 16B per lane; LDS dest = wave-uniform base + lane*16
#define GLOAD16(g, l) __builtin_amdgcn_global_load_lds( \
    (const __attribute__((address_space(1))) unsigned int*)(g), \
    (__attribute__((address_space(3))) unsigned int*)(l), 16, 0, 0)

__device__ inline ushort_t f2bf(float f) {
    __hip_bfloat16 h = __float2bfloat16(f);
    return *reinterpret_cast<ushort_t*>(&h);
}

// ---------------------------------------------------------------------------
__global__ __launch_bounds__(256) void zero_kernel(float* __restrict__ p, int n) {
    int i = blockIdx.x * 256 + threadIdx.x;
    if (i < n) p[i] = 0.0f;
}

// ---------------------------------------------------------------------------
// fp32 -> bf16 conversion: y selects tensor. 8 elements/thread.
__global__ __launch_bounds__(256) void cvt_bf16(
    const float* __restrict__ x1, const float* __restrict__ x2,
    const float* __restrict__ Wq, const float* __restrict__ Wk,
    const float* __restrict__ Wv,
    ushort_t* __restrict__ xb1, ushort_t* __restrict__ xb2,
    ushort_t* __restrict__ Wqb, ushort_t* __restrict__ Wkb,
    ushort_t* __restrict__ Wvb)
{
    const float* s; ushort_t* d; int n;
    switch (blockIdx.y) {
        case 0: s = x1; d = xb1; n = 16777216; break;
        case 1: s = x2; d = xb2; n = 16777216; break;
        case 2: s = Wq; d = Wqb; n = 65536; break;
        case 3: s = Wk; d = Wkb; n = 65536; break;
        default: s = Wv; d = Wvb; n = 65536; break;
    }
    int i = (blockIdx.x * 256 + threadIdx.x) * 8;
    if (i >= n) return;
    float4 a = *(const float4*)&s[i];
    float4 b = *(const float4*)&s[i + 4];
    u16x8 o;
    o[0] = f2bf(a.x); o[1] = f2bf(a.y); o[2] = f2bf(a.z); o[3] = f2bf(a.w);
    o[4] = f2bf(b.x); o[5] = f2bf(b.y); o[6] = f2bf(b.z); o[7] = f2bf(b.w);
    *(u16x8*)&d[i] = o;
}

// ---------------------------------------------------------------------------
// MFMA projection GEMM: out[m][c] = sum_k A[m][k]*W[c][k], all bf16 in, bf16 out.
// 128x128 tile, BK=64, 4 waves (2x2 of 64x64), fused column sum-of-squares.
// z=0: q (ss=ssq), z=1: k (ss=ssk), z=2: v.
__global__ __launch_bounds__(256) void proj_mfma(
    const ushort_t* __restrict__ xb1, const ushort_t* __restrict__ xb2,
    const ushort_t* __restrict__ Wqb, const ushort_t* __restrict__ Wkb,
    const ushort_t* __restrict__ Wvb,
    ushort_t* __restrict__ qp, ushort_t* __restrict__ kp, ushort_t* __restrict__ vp,
    float* __restrict__ ssq, float* __restrict__ ssk)
{
    const ushort_t* A; const ushort_t* W; ushort_t* outp; float* ss;
    if (blockIdx.z == 0)      { A = xb1; W = Wqb; outp = qp; ss = ssq; }
    else if (blockIdx.z == 1) { A = xb2; W = Wkb; outp = kp; ss = ssk; }
    else                      { A = xb2; W = Wvb; outp = vp; ss = nullptr; }

    // LDS layout: 16B slot index = kg*128 + row   (kg = k/8 within BK=64 slice)
    __shared__ ushort_t Asl[8192];   // 16 KB
    __shared__ ushort_t Bsl[8192];   // 16 KB
    __shared__ float colss[128];

    const int t = threadIdx.x;
    const int lane = t & 63, w = t >> 6;
    const int l16 = lane & 15, quad = lane >> 4;
    const int m0 = blockIdx.x * 128;
    const int c0 = blockIdx.y * 128;
    const int wm = (w >> 1) * 64, wn = (w & 1) * 64;

    f32x4 acc[4][4] = {};

    for (int k0 = 0; k0 < CDIM; k0 += 64) {
        __syncthreads();
#pragma unroll
        for (int r = 0; r < 4; ++r) {
            int slot = r * 256 + t;
            int kg = slot >> 7, m = slot & 127;
            GLOAD16(A + (size_t)(m0 + m) * CDIM + k0 + kg * 8,
                    &Asl[(size_t)(r * 256 + w * 64) * 8]);
        }
#pragma unroll
        for (int r = 0; r < 4; ++r) {
            int slot = r * 256 + t;
            int kg = slot >> 7, c = slot & 127;
            GLOAD16(W + (size_t)(c0 + c) * CDIM + k0 + kg * 8,
                    &Bsl[(size_t)(r * 256 + w * 64) * 8]);
        }
        __syncthreads();
#pragma unroll
        for (int ks = 0; ks < 2; ++ks) {
            const int kg = ks * 4 + quad;
            bf16x8 aF[4], bF[4];
#pragma unroll
            for (int i = 0; i < 4; ++i)
                aF[i] = *(const bf16x8*)&Asl[(size_t)(kg * 128 + wm + i * 16 + l16) * 8];
#pragma unroll
            for (int j = 0; j < 4; ++j)
                bF[j] = *(const bf16x8*)&Bsl[(size_t)(kg * 128 + wn + j * 16 + l16) * 8];
#pragma unroll
            for (int i = 0; i < 4; ++i)
#pragma unroll
                for (int j = 0; j < 4; ++j)
                    acc[i][j] = __builtin_amdgcn_mfma_f32_16x16x32_bf16(aF[i], bF[j], acc[i][j], 0, 0, 0);
        }
    }

    // epilogue: C/D layout col=lane&15, row=quad*4+reg
#pragma unroll
    for (int i = 0; i < 4; ++i) {
#pragma unroll
        for (int j = 0; j < 4; ++j) {
            int col = c0 + wn + j * 16 + l16;
#pragma unroll
            for (int reg = 0; reg < 4; ++reg) {
                int row = m0 + wm + i * 16 + quad * 4 + reg;
                outp[(size_t)row * CDIM + col] = f2bf(acc[i][j][reg]);
            }
        }
    }

    if (ss) {
        if (t < 128) colss[t] = 0.0f;
        __syncthreads();
#pragma unroll
        for (int j = 0; j < 4; ++j) {
            float s = 0.0f;
#pragma unroll
            for (int i = 0; i < 4; ++i)
#pragma unroll
                for (int reg = 0; reg < 4; ++reg)
                    s += acc[i][j][reg] * acc[i][j][reg];
            atomicAdd(&colss[wn + j * 16 + l16], s);
        }
        __syncthreads();
        if (t < 128) {
            int b = m0 >> 13;   // 128-row tile never crosses a batch
            atomicAdd(&ss[b * CDIM + c0 + t], colss[t]);
        }
    }
}

// ---------------------------------------------------------------------------
// MFMA Gram: G[b][h][d][e] += sum_n qp[b][n][h*64+d] * kp[b][n][h*64+e]
// grid (16 slabs, H, B). Stage [64 c][128 n] transposed in LDS (stride 144),
// each wave owns a 32-token chunk; LDS reduce across waves; global atomics.
__global__ __launch_bounds__(256) void gram_mfma(
    const ushort_t* __restrict__ qp, const ushort_t* __restrict__ kp,
    float* __restrict__ G)
{
    constexpr int NS = 144;  // padded n-stride (16B-aligned, b128-conflict-free)
    __shared__ ushort_t qs[64 * NS];   // 18 KB
    __shared__ ushort_t ks2[64 * NS];  // 18 KB
    __shared__ float gsum[4096];       // 16 KB

    const int t = threadIdx.x;
    const int lane = t & 63, w = t >> 6;
    const int l16 = lane & 15, quad = lane >> 4;
    const int slab = blockIdx.x, h = blockIdx.y, b = blockIdx.z;
    const size_t base = (size_t)b * NTOK * CDIM + h * DHEAD;

    for (int i = t; i < 4096; i += 256) gsum[i] = 0.0f;

    f32x4 acc[4][4] = {};

    for (int n0 = slab * 512; n0 < slab * 512 + 512; n0 += 128) {
        __syncthreads();
#pragma unroll
        for (int r = 0; r < 4; ++r) {
            int idx = r * 256 + t;          // 0..1023
            int n = idx & 127, c8 = idx >> 7;
            size_t g = base + (size_t)(n0 + n) * CDIM + c8 * 8;
            ushort4 qa = *(const ushort4*)&qp[g];
            ushort4 qb = *(const ushort4*)&qp[g + 4];
            ushort4 ka = *(const ushort4*)&kp[g];
            ushort4 kb = *(const ushort4*)&kp[g + 4];
            int c = c8 * 8;
            qs[(c + 0) * NS + n] = qa.x; qs[(c + 1) * NS + n] = qa.y;
            qs[(c + 2) * NS + n] = qa.z; qs[(c + 3) * NS + n] = qa.w;
            qs[(c + 4) * NS + n] = qb.x; qs[(c + 5) * NS + n] = qb.y;
            qs[(c + 6) * NS + n] = qb.z; qs[(c + 7) * NS + n] = qb.w;
            ks2[(c + 0) * NS + n] = ka.x; ks2[(c + 1) * NS + n] = ka.y;
            ks2[(c + 2) * NS + n] = ka.z; ks2[(c + 3) * NS + n] = ka.w;
            ks2[(c + 4) * NS + n] = kb.x; ks2[(c + 5) * NS + n] = kb.y;
            ks2[(c + 6) * NS + n] = kb.z; ks2[(c + 7) * NS + n] = kb.w;
        }
        __syncthreads();
        // wave w computes tokens [w*32, w*32+32): A[m=d][k=n], B[k=n][col=e]
        bf16x8 aF[4], bF[4];
#pragma unroll
        for (int i = 0; i < 4; ++i)
            aF[i] = *(const bf16x8*)&qs[(i * 16 + l16) * NS + w * 32 + quad * 8];
#pragma unroll
        for (int j = 0; j < 4; ++j)
            bF[j] = *(const bf16x8*)&ks2[(j * 16 + l16) * NS + w * 32 + quad * 8];
#pragma unroll
        for (int i = 0; i < 4; ++i)
#pragma unroll
            for (int j = 0; j < 4; ++j)
                acc[i][j] = __builtin_amdgcn_mfma_f32_16x16x32_bf16(aF[i], bF[j], acc[i][j], 0, 0, 0);
    }

    __syncthreads();
#pragma unroll
    for (int i = 0; i < 4; ++i)
#pragma unroll
        for (int j = 0; j < 4; ++j)
#pragma unroll
            for (int reg = 0; reg < 4; ++reg)
                atomicAdd(&gsum[(i * 16 + quad * 4 + reg) * 64 + j * 16 + l16], acc[i][j][reg]);
    __syncthreads();

    float* Gp = G + (size_t)(b * HEADS + h) * 4096;
    for (int i = t; i < 4096; i += 256) atomicAdd(&Gp[i], gsum[i]);
}

// ---------------------------------------------------------------------------
// K3: normalize, temperature, row softmax (unchanged)
__global__ __launch_bounds__(64) void attn_softmax(
    float* __restrict__ G, const float* __restrict__ ssq,
    const float* __restrict__ ssk, const float* __restrict__ temp)
{
    const int h = blockIdx.x, b = blockIdx.y;
    const int d = threadIdx.x;
    __shared__ float nk[64];

    float nq = fmaxf(sqrtf(ssq[b * CDIM + h * DHEAD + d]), 1e-12f);
    nk[d]    = fmaxf(sqrtf(ssk[b * CDIM + h * DHEAD + d]), 1e-12f);
    __syncthreads();

    float* row = G + (size_t)(b * HEADS + h) * DHEAD * DHEAD + d * DHEAD;
    const float tmp = temp[h];

    float vals[64];
    float mx = -1e30f;
#pragma unroll
    for (int e = 0; e < 64; ++e) {
        float v = row[e] / (nq * nk[e]) * tmp;
        vals[e] = v;
        mx = fmaxf(mx, v);
    }
    float s = 0.0f;
#pragma unroll
    for (int e = 0; e < 64; ++e) {
        float ev = __expf(vals[e] - mx);
        vals[e] = ev;
        s += ev;
    }
    float inv = 1.0f / s;
#pragma unroll
    for (int e = 0; e < 64; ++e) row[e] = vals[e] * inv;
}

// ---------------------------------------------------------------------------
// K4: W_eff[b][c][h*64+e] = sum_d Wo[c][h*64+d] * attn[b][h][d][e], bf16 out
__global__ __launch_bounds__(256) void weff_kernel(
    const float* __restrict__ Wo, const float* __restrict__ attn,
    ushort_t* __restrict__ Weffb)
{
    const int h = blockIdx.x, b = blockIdx.y;
    const int c = threadIdx.x;
    __shared__ float at[64][65];

    const float* Ab = attn + (size_t)(b * HEADS + h) * DHEAD * DHEAD;
    for (int idx = c; idx < DHEAD * DHEAD; idx += 256)
        at[idx >> 6][idx & 63] = Ab[idx];
    __syncthreads();

    float wo[64];
#pragma unroll
    for (int d2 = 0; d2 < 64; ++d2) wo[d2] = Wo[(size_t)c * CDIM + h * DHEAD + d2];

    ushort_t* Wb = Weffb + (size_t)b * CDIM * CDIM + (size_t)c * CDIM + h * DHEAD;
#pragma unroll 4
    for (int e = 0; e < 64; ++e) {
        float s = 0.0f;
#pragma unroll
        for (int d2 = 0; d2 < 64; ++d2) s += wo[d2] * at[d2][e];
        Wb[e] = f2bf(s);
    }
}

// ---------------------------------------------------------------------------
// MFMA output GEMM: out[m][c] = bo[c] + sum_k vp[m][k]*Weffb[b][c][k], b=m/NTOK
__global__ __launch_bounds__(256) void out_mfma(
    const ushort_t* __restrict__ vp, const ushort_t* __restrict__ Weffb,
    const float* __restrict__ bo, float* __restrict__ out)
{
    __shared__ ushort_t Asl[8192];
    __shared__ ushort_t Bsl[8192];

    const int t = threadIdx.x;
    const int lane = t & 63, w = t >> 6;
    const int l16 = lane & 15, quad = lane >> 4;
    const int m0 = blockIdx.x * 128;
    const int c0 = blockIdx.y * 128;
    const int wm = (w >> 1) * 64, wn = (w & 1) * 64;
    const ushort_t* Wb = Weffb + (size_t)(m0 >> 13) * CDIM * CDIM;

    f32x4 acc[4][4] = {};

    for (int k0 = 0; k0 < CDIM; k0 += 64) {
        __syncthreads();
#pragma unroll
        for (int r = 0; r < 4; ++r) {
            int slot = r * 256 + t;
            int kg = slot >> 7, m = slot & 127;
            GLOAD16(vp + (size_t)(m0 + m) * CDIM + k0 + kg * 8,
                    &Asl[(size_t)(r * 256 + w * 64) * 8]);
        }
#pragma unroll
        for (int r = 0; r < 4; ++r) {
            int slot = r * 256 + t;
            int kg = slot >> 7, c = slot & 127;
            GLOAD16(Wb + (size_t)(c0 + c) * CDIM + k0 + kg * 8,
                    &Bsl[(size_t)(r * 256 + w * 64) * 8]);
        }
        __syncthreads();
#pragma unroll
        for (int ks = 0; ks < 2; ++ks) {
            const int kg = ks * 4 + quad;
            bf16x8 aF[4], bF[4];
#pragma unroll
            for (int i = 0; i < 4; ++i)
                aF[i] = *(const bf16x8*)&Asl[(size_t)(kg * 128 + wm + i * 16 + l16) * 8];
#pragma unroll
            for (int j = 0; j < 4; ++j)
                bF[j] = *(const bf16x8*)&Bsl[(size_t)(kg * 128 + wn + j * 16 + l16) * 8];
#pragma unroll
            for (int i = 0; i < 4; ++i)
#pragma unroll
                for (int j = 0; j < 4; ++j)
                    acc[i][j] = __builtin_amdgcn_mfma_f32_16x16x32_bf16(aF[i], bF[j], acc[i][j], 0, 0, 0);
        }
    }

#pragma unroll
    for (int i = 0; i < 4; ++i) {
#pragma unroll
        for (int j = 0; j < 4; ++j) {
            int col = c0 + wn + j * 16 + l16;
            float bias = bo[col];
#pragma unroll
            for (int reg = 0; reg < 4; ++reg) {
                int row = m0 + wm + i * 16 + quad * 4 + reg;
                out[(size_t)row * CDIM + col] = acc[i][j][reg] + bias;
            }
        }
    }
}

// ---------------------------------------------------------------------------
extern "C" void kernel_launch(void* const* d_in, const int* in_sizes, int n_in,
                              void* d_out, int out_size, void* d_ws, size_t ws_size,
                              hipStream_t stream) {
    const float* x1   = (const float*)d_in[0];
    const float* x2   = (const float*)d_in[1];
    const float* Wq   = (const float*)d_in[2];
    const float* Wk   = (const float*)d_in[3];
    const float* Wv   = (const float*)d_in[4];
    const float* Wo   = (const float*)d_in[5];
    const float* bo   = (const float*)d_in[6];
    const float* temp = (const float*)d_in[7];
    float* out = (float*)d_out;

    char* ws = (char*)d_ws;
    const size_t SZP = (size_t)MROWS * CDIM * sizeof(ushort_t);   // 32 MB
    ushort_t* qp   = (ushort_t*)(ws);
    ushort_t* kp   = (ushort_t*)(ws + SZP);
    ushort_t* vp   = (ushort_t*)(ws + 2 * SZP);
    ushort_t* xb1  = (ushort_t*)(ws + 3 * SZP);
    ushort_t* xb2  = (ushort_t*)(ws + 4 * SZP);
    ushort_t* Wqb  = (ushort_t*)(ws + 5 * SZP);
    ushort_t* Wkb  = (ushort_t*)(ws + 5 * SZP + 131072);
    ushort_t* Wvb  = (ushort_t*)(ws + 5 * SZP + 262144);
    float*    ssq  = (float*)(ws + 5 * SZP + 393216);
    float*    ssk  = (float*)(ws + 5 * SZP + 401408);
    float*    G    = (float*)(ws + 5 * SZP + 409600);
    ushort_t* Weffb= (ushort_t*)(ws + 5 * SZP + 933888);

    // zero ssq+ssk+G (contiguous, 135168 floats)
    zero_kernel<<<dim3((135168 + 255) / 256), dim3(256), 0, stream>>>(ssq, 135168);

    cvt_bf16<<<dim3(8192, 5), dim3(256), 0, stream>>>(
        x1, x2, Wq, Wk, Wv, xb1, xb2, Wqb, Wkb, Wvb);

    proj_mfma<<<dim3(MROWS / 128, CDIM / 128, 3), dim3(256), 0, stream>>>(
        xb1, xb2, Wqb, Wkb, Wvb, qp, kp, vp, ssq, ssk);

    gram_mfma<<<dim3(16, HEADS, BDIM), dim3(256), 0, stream>>>(qp, kp, G);

    attn_softmax<<<dim3(HEADS, BDIM), dim3(64), 0, stream>>>(G, ssq, ssk, temp);

    weff_kernel<<<dim3(HEADS, BDIM), dim3(256), 0, stream>>>(Wo, G, Weffb);

    out_mfma<<<dim3(MROWS / 128, CDIM / 128), dim3(256), 0, stream>>>(vp, Weffb, bo, out);
}

// Round 3
// 350.916 us; speedup vs baseline: 2.0278x; 1.0481x over previous
//
#include <hip/hip_runtime.h>
#include <hip/hip_bf16.h>

#define BDIM 8
#define NTOK 8192
#define CDIM 256
#define HEADS 4
#define DHEAD 64
#define MROWS (BDIM * NTOK)   // 65536

typedef unsigned short ushort_t;
typedef short bf16x8 __attribute__((ext_vector_type(8)));
typedef float f32x4 __attribute__((ext_vector_type(4)));
typedef unsigned short u16x8 __attribute__((ext_vector_type(8)));
typedef unsigned short u16x4 __attribute__((ext_vector_type(4)));

__device__ inline ushort_t f2bf(float f) {
    __hip_bfloat16 h = __float2bfloat16(f);
    return *reinterpret_cast<ushort_t*>(&h);
}

__device__ inline u16x8 pack8(float4 a, float4 b) {
    u16x8 o;
    o[0] = f2bf(a.x); o[1] = f2bf(a.y); o[2] = f2bf(a.z); o[3] = f2bf(a.w);
    o[4] = f2bf(b.x); o[5] = f2bf(b.y); o[6] = f2bf(b.z); o[7] = f2bf(b.w);
    return o;
}

// ---------------------------------------------------------------------------
__global__ __launch_bounds__(256) void zero_kernel(float* __restrict__ p, int n) {
    int i = blockIdx.x * 256 + threadIdx.x;
    if (i < n) p[i] = 0.0f;
}

// ---------------------------------------------------------------------------
// Pipelined MFMA projection: out[m][c] = sum_k A[m][k]*W[c][k], fp32 in, bf16 out.
// 128x128 tile, BK=32 (8 iters), VGPR-prefetch staging + in-reg fp32->bf16 cvt,
// double-buffered LDS, ONE raw s_barrier per iter (no vmcnt drain -> loads fly
// across the barrier). Fused per-column sum-of-squares.
__global__ __launch_bounds__(256) void proj_mfma(
    const float* __restrict__ x1, const float* __restrict__ x2,
    const float* __restrict__ Wq, const float* __restrict__ Wk,
    const float* __restrict__ Wv,
    ushort_t* __restrict__ qp, ushort_t* __restrict__ kp, ushort_t* __restrict__ vp,
    float* __restrict__ ssq, float* __restrict__ ssk)
{
    const float* A; const float* W; ushort_t* outp; float* ss;
    if (blockIdx.z == 0)      { A = x1; W = Wq; outp = qp; ss = ssq; }
    else if (blockIdx.z == 1) { A = x2; W = Wk; outp = kp; ss = ssk; }
    else                      { A = x2; W = Wv; outp = vp; ss = nullptr; }

    // LDS 16B-slot layout per buffer: slot = kg*128 + row (kg = k/8 within BK=32)
    __shared__ ushort_t Asl[2][4096];   // 2 x 8 KB
    __shared__ ushort_t Bsl[2][4096];
    __shared__ float colss[128];

    const int t = threadIdx.x;
    const int lane = t & 63, w = t >> 6;
    const int l16 = lane & 15, quad = lane >> 4;
    const int m0 = blockIdx.x * 128, c0 = blockIdx.y * 128;
    const int wm = (w >> 1) * 64, wn = (w & 1) * 64;

    const int srow = t >> 1;   // 0..127
    const int skh  = t & 1;    // k-half: floats [skh*16, skh*16+16)

    const float* Ap = A + (size_t)(m0 + srow) * CDIM + skh * 16;
    const float* Wp = W + (size_t)(c0 + srow) * CDIM + skh * 16;

    float4 ga[4], gb[4];
#pragma unroll
    for (int i = 0; i < 4; ++i) {
        ga[i] = *(const float4*)(Ap + i * 4);
        gb[i] = *(const float4*)(Wp + i * 4);
    }

    f32x4 acc[4][4] = {};

#pragma unroll 2
    for (int it = 0; it < 8; ++it) {
        ushort_t* As = Asl[it & 1];
        ushort_t* Bs = Bsl[it & 1];
        *(u16x8*)&As[(skh * 2 + 0) * 1024 + srow * 8] = pack8(ga[0], ga[1]);
        *(u16x8*)&As[(skh * 2 + 1) * 1024 + srow * 8] = pack8(ga[2], ga[3]);
        *(u16x8*)&Bs[(skh * 2 + 0) * 1024 + srow * 8] = pack8(gb[0], gb[1]);
        *(u16x8*)&Bs[(skh * 2 + 1) * 1024 + srow * 8] = pack8(gb[2], gb[3]);
        if (it < 7) {
            int ko = (it + 1) * 32;
#pragma unroll
            for (int i = 0; i < 4; ++i) {
                ga[i] = *(const float4*)(Ap + ko + i * 4);
                gb[i] = *(const float4*)(Wp + ko + i * 4);
            }
        }
        asm volatile("s_waitcnt lgkmcnt(0)" ::: "memory");
        __builtin_amdgcn_s_barrier();
        bf16x8 aF[4], bF[4];
#pragma unroll
        for (int i = 0; i < 4; ++i)
            aF[i] = *(const bf16x8*)&As[quad * 1024 + (wm + i * 16 + l16) * 8];
#pragma unroll
        for (int j = 0; j < 4; ++j)
            bF[j] = *(const bf16x8*)&Bs[quad * 1024 + (wn + j * 16 + l16) * 8];
#pragma unroll
        for (int i = 0; i < 4; ++i)
#pragma unroll
            for (int j = 0; j < 4; ++j)
                acc[i][j] = __builtin_amdgcn_mfma_f32_16x16x32_bf16(aF[i], bF[j], acc[i][j], 0, 0, 0);
    }

    // epilogue: C/D layout col=lane&15, row=quad*4+reg
#pragma unroll
    for (int i = 0; i < 4; ++i) {
#pragma unroll
        for (int j = 0; j < 4; ++j) {
            int col = c0 + wn + j * 16 + l16;
#pragma unroll
            for (int reg = 0; reg < 4; ++reg) {
                int row = m0 + wm + i * 16 + quad * 4 + reg;
                outp[(size_t)row * CDIM + col] = f2bf(acc[i][j][reg]);
            }
        }
    }

    if (ss) {
        __syncthreads();
        if (t < 128) colss[t] = 0.0f;
        __syncthreads();
#pragma unroll
        for (int j = 0; j < 4; ++j) {
            float s = 0.0f;
#pragma unroll
            for (int i = 0; i < 4; ++i)
#pragma unroll
                for (int reg = 0; reg < 4; ++reg)
                    s += acc[i][j][reg] * acc[i][j][reg];
            atomicAdd(&colss[wn + j * 16 + l16], s);
        }
        __syncthreads();
        if (t < 128) {
            int b = m0 >> 13;   // 128-row tile never crosses a batch
            atomicAdd(&ss[b * CDIM + c0 + t], colss[t]);
        }
    }
}

// ---------------------------------------------------------------------------
// MFMA Gram: G[b][h][d][e] += sum_n qp[b][n][h*64+d] * kp[b][n][h*64+e]
// grid (16 slabs, H, B). Stage [64 c][128 n] transposed in LDS (stride 144),
// vectorized: 4-token in-register transpose -> ds_write_b64.
__global__ __launch_bounds__(256) void gram_mfma(
    const ushort_t* __restrict__ qp, const ushort_t* __restrict__ kp,
    float* __restrict__ G)
{
    constexpr int NS = 144;  // padded n-stride (16B-aligned, b128-conflict-free)
    __shared__ ushort_t qs[64 * NS];   // 18 KB
    __shared__ ushort_t ks2[64 * NS];  // 18 KB
    __shared__ float gsum[4096];       // 16 KB

    const int t = threadIdx.x;
    const int lane = t & 63, w = t >> 6;
    const int l16 = lane & 15, quad = lane >> 4;
    const int slab = blockIdx.x, h = blockIdx.y, b = blockIdx.z;
    const size_t base = (size_t)b * NTOK * CDIM + h * DHEAD;

    const int cg  = t >> 5;   // 0..7 -> channels cg*8..+7
    const int ng4 = t & 31;   // 0..31 -> tokens ng4*4..+3

    for (int i = t; i < 4096; i += 256) gsum[i] = 0.0f;

    f32x4 acc[4][4] = {};

    for (int n0 = slab * 512; n0 < slab * 512 + 512; n0 += 128) {
        u16x8 qv[4], kv[4];
#pragma unroll
        for (int i = 0; i < 4; ++i) {
            size_t g = base + (size_t)(n0 + ng4 * 4 + i) * CDIM + cg * 8;
            qv[i] = *(const u16x8*)&qp[g];
            kv[i] = *(const u16x8*)&kp[g];
        }
        __syncthreads();
#pragma unroll
        for (int j = 0; j < 8; ++j) {
            u16x4 wq, wk;
            wq[0] = qv[0][j]; wq[1] = qv[1][j]; wq[2] = qv[2][j]; wq[3] = qv[3][j];
            wk[0] = kv[0][j]; wk[1] = kv[1][j]; wk[2] = kv[2][j]; wk[3] = kv[3][j];
            *(u16x4*)&qs[(cg * 8 + j) * NS + ng4 * 4] = wq;
            *(u16x4*)&ks2[(cg * 8 + j) * NS + ng4 * 4] = wk;
        }
        __syncthreads();
        // wave w computes tokens [w*32, w*32+32): A[m=d][k=n], B[k=n][col=e]
        bf16x8 aF[4], bF[4];
#pragma unroll
        for (int i = 0; i < 4; ++i)
            aF[i] = *(const bf16x8*)&qs[(i * 16 + l16) * NS + w * 32 + quad * 8];
#pragma unroll
        for (int j = 0; j < 4; ++j)
            bF[j] = *(const bf16x8*)&ks2[(j * 16 + l16) * NS + w * 32 + quad * 8];
#pragma unroll
        for (int i = 0; i < 4; ++i)
#pragma unroll
            for (int j = 0; j < 4; ++j)
                acc[i][j] = __builtin_amdgcn_mfma_f32_16x16x32_bf16(aF[i], bF[j], acc[i][j], 0, 0, 0);
    }

    __syncthreads();
#pragma unroll
    for (int i = 0; i < 4; ++i)
#pragma unroll
        for (int j = 0; j < 4; ++j)
#pragma unroll
            for (int reg = 0; reg < 4; ++reg)
                atomicAdd(&gsum[(i * 16 + quad * 4 + reg) * 64 + j * 16 + l16], acc[i][j][reg]);
    __syncthreads();

    float* Gp = G + (size_t)(b * HEADS + h) * 4096;
    for (int i = t; i < 4096; i += 256) atomicAdd(&Gp[i], gsum[i]);
}

// ---------------------------------------------------------------------------
// K3: normalize, temperature, row softmax
__global__ __launch_bounds__(64) void attn_softmax(
    float* __restrict__ G, const float* __restrict__ ssq,
    const float* __restrict__ ssk, const float* __restrict__ temp)
{
    const int h = blockIdx.x, b = blockIdx.y;
    const int d = threadIdx.x;
    __shared__ float nk[64];

    float nq = fmaxf(sqrtf(ssq[b * CDIM + h * DHEAD + d]), 1e-12f);
    nk[d]    = fmaxf(sqrtf(ssk[b * CDIM + h * DHEAD + d]), 1e-12f);
    __syncthreads();

    float* row = G + (size_t)(b * HEADS + h) * DHEAD * DHEAD + d * DHEAD;
    const float tmp = temp[h];

    float vals[64];
    float mx = -1e30f;
#pragma unroll
    for (int e = 0; e < 64; ++e) {
        float v = row[e] / (nq * nk[e]) * tmp;
        vals[e] = v;
        mx = fmaxf(mx, v);
    }
    float s = 0.0f;
#pragma unroll
    for (int e = 0; e < 64; ++e) {
        float ev = __expf(vals[e] - mx);
        vals[e] = ev;
        s += ev;
    }
    float inv = 1.0f / s;
#pragma unroll
    for (int e = 0; e < 64; ++e) row[e] = vals[e] * inv;
}

// ---------------------------------------------------------------------------
// K4: W_eff[b][c][h*64+e] = sum_d Wo[c][h*64+d] * attn[b][h][d][e], bf16 out
__global__ __launch_bounds__(256) void weff_kernel(
    const float* __restrict__ Wo, const float* __restrict__ attn,
    ushort_t* __restrict__ Weffb)
{
    const int h = blockIdx.x, b = blockIdx.y;
    const int c = threadIdx.x;
    __shared__ float at[64][65];

    const float* Ab = attn + (size_t)(b * HEADS + h) * DHEAD * DHEAD;
    for (int idx = c; idx < DHEAD * DHEAD; idx += 256)
        at[idx >> 6][idx & 63] = Ab[idx];
    __syncthreads();

    float wo[64];
#pragma unroll
    for (int d2 = 0; d2 < 64; ++d2) wo[d2] = Wo[(size_t)c * CDIM + h * DHEAD + d2];

    ushort_t* Wb = Weffb + (size_t)b * CDIM * CDIM + (size_t)c * CDIM + h * DHEAD;
#pragma unroll 4
    for (int e = 0; e < 64; ++e) {
        float s = 0.0f;
#pragma unroll
        for (int d2 = 0; d2 < 64; ++d2) s += wo[d2] * at[d2][e];
        Wb[e] = f2bf(s);
    }
}

// ---------------------------------------------------------------------------
// Pipelined MFMA output GEMM: out[m][c] = bo[c] + sum_k vp[m][k]*Weffb[b][c][k]
// Same single-barrier dbuf skeleton as proj_mfma, bf16 inputs (no cvt).
__global__ __launch_bounds__(256) void out_mfma(
    const ushort_t* __restrict__ vp, const ushort_t* __restrict__ Weffb,
    const float* __restrict__ bo, float* __restrict__ out)
{
    __shared__ ushort_t Asl[2][4096];
    __shared__ ushort_t Bsl[2][4096];

    const int t = threadIdx.x;
    const int lane = t & 63, w = t >> 6;
    const int l16 = lane & 15, quad = lane >> 4;
    const int m0 = blockIdx.x * 128, c0 = blockIdx.y * 128;
    const int wm = (w >> 1) * 64, wn = (w & 1) * 64;

    const int srow = t >> 1;
    const int skh  = t & 1;

    const ushort_t* Ap = vp + (size_t)(m0 + srow) * CDIM + skh * 16;
    const ushort_t* Bp = Weffb + (size_t)(m0 >> 13) * CDIM * CDIM
                       + (size_t)(c0 + srow) * CDIM + skh * 16;

    u16x8 ga0 = *(const u16x8*)Ap,       ga1 = *(const u16x8*)(Ap + 8);
    u16x8 gb0 = *(const u16x8*)Bp,       gb1 = *(const u16x8*)(Bp + 8);

    f32x4 acc[4][4] = {};

#pragma unroll 2
    for (int it = 0; it < 8; ++it) {
        ushort_t* As = Asl[it & 1];
        ushort_t* Bs = Bsl[it & 1];
        *(u16x8*)&As[(skh * 2 + 0) * 1024 + srow * 8] = ga0;
        *(u16x8*)&As[(skh * 2 + 1) * 1024 + srow * 8] = ga1;
        *(u16x8*)&Bs[(skh * 2 + 0) * 1024 + srow * 8] = gb0;
        *(u16x8*)&Bs[(skh * 2 + 1) * 1024 + srow * 8] = gb1;
        if (it < 7) {
            int ko = (it + 1) * 32;
            ga0 = *(const u16x8*)(Ap + ko);
            ga1 = *(const u16x8*)(Ap + ko + 8);
            gb0 = *(const u16x8*)(Bp + ko);
            gb1 = *(const u16x8*)(Bp + ko + 8);
        }
        asm volatile("s_waitcnt lgkmcnt(0)" ::: "memory");
        __builtin_amdgcn_s_barrier();
        bf16x8 aF[4], bF[4];
#pragma unroll
        for (int i = 0; i < 4; ++i)
            aF[i] = *(const bf16x8*)&As[quad * 1024 + (wm + i * 16 + l16) * 8];
#pragma unroll
        for (int j = 0; j < 4; ++j)
            bF[j] = *(const bf16x8*)&Bs[quad * 1024 + (wn + j * 16 + l16) * 8];
#pragma unroll
        for (int i = 0; i < 4; ++i)
#pragma unroll
            for (int j = 0; j < 4; ++j)
                acc[i][j] = __builtin_amdgcn_mfma_f32_16x16x32_bf16(aF[i], bF[j], acc[i][j], 0, 0, 0);
    }

#pragma unroll
    for (int i = 0; i < 4; ++i) {
#pragma unroll
        for (int j = 0; j < 4; ++j) {
            int col = c0 + wn + j * 16 + l16;
            float bias = bo[col];
#pragma unroll
            for (int reg = 0; reg < 4; ++reg) {
                int row = m0 + wm + i * 16 + quad * 4 + reg;
                out[(size_t)row * CDIM + col] = acc[i][j][reg] + bias;
            }
        }
    }
}

// ---------------------------------------------------------------------------
extern "C" void kernel_launch(void* const* d_in, const int* in_sizes, int n_in,
                              void* d_out, int out_size, void* d_ws, size_t ws_size,
                              hipStream_t stream) {
    const float* x1   = (const float*)d_in[0];
    const float* x2   = (const float*)d_in[1];
    const float* Wq   = (const float*)d_in[2];
    const float* Wk   = (const float*)d_in[3];
    const float* Wv   = (const float*)d_in[4];
    const float* Wo   = (const float*)d_in[5];
    const float* bo   = (const float*)d_in[6];
    const float* temp = (const float*)d_in[7];
    float* out = (float*)d_out;

    char* ws = (char*)d_ws;
    const size_t SZP = (size_t)MROWS * CDIM * sizeof(ushort_t);   // 32 MB
    ushort_t* qp   = (ushort_t*)(ws);
    ushort_t* kp   = (ushort_t*)(ws + SZP);
    ushort_t* vp   = (ushort_t*)(ws + 2 * SZP);
    float*    ssq  = (float*)(ws + 3 * SZP);                 // 8 KB
    float*    ssk  = (float*)(ws + 3 * SZP + 8192);          // 8 KB
    float*    G    = (float*)(ws + 3 * SZP + 16384);         // 512 KB
    ushort_t* Weffb= (ushort_t*)(ws + 3 * SZP + 540672);     // 1 MB

    // zero ssq+ssk+G (contiguous, 135168 floats)
    zero_kernel<<<dim3((135168 + 255) / 256), dim3(256), 0, stream>>>(ssq, 135168);

    proj_mfma<<<dim3(MROWS / 128, CDIM / 128, 3), dim3(256), 0, stream>>>(
        x1, x2, Wq, Wk, Wv, qp, kp, vp, ssq, ssk);

    gram_mfma<<<dim3(16, HEADS, BDIM), dim3(256), 0, stream>>>(qp, kp, G);

    attn_softmax<<<dim3(HEADS, BDIM), dim3(64), 0, stream>>>(G, ssq, ssk, temp);

    weff_kernel<<<dim3(HEADS, BDIM), dim3(256), 0, stream>>>(Wo, G, Weffb);

    out_mfma<<<dim3(MROWS / 128, CDIM / 128), dim3(256), 0, stream>>>(vp, Weffb, bo, out);
}